// Round 1
// baseline (708.599 us; speedup 1.0000x reference)
//
#include <hip/hip_runtime.h>

// Problem constants (from reference): B=32, N=512, D=256, M=64, HID=256, H2=128, T=16384
#define BATCH 32
#define NINST 512
#define DDIM  256
#define MDIM  64
#define HID   256
#define H2DIM 128
#define TMET  16384

// ---------------------------------------------------------------------------
// Kernel 1: A[b*N+n][h] = dot(h_inst[b*N+n][0:256], W1[0:256][h]) + b1[h]
// M = B*N = 16384 rows, K = 256, N = 256.  2.1 GFLOP fp32.
// Block: 256 threads, 32 rows x 256 cols per block. 512 blocks.
// ---------------------------------------------------------------------------
__global__ __launch_bounds__(256) void precomp_inst(
    const float* __restrict__ X,   // [B*N, 256]
    const float* __restrict__ W1,  // [320, 256] (rows 0..255 used here)
    const float* __restrict__ b1,  // [256]
    float* __restrict__ A)         // [B*N, 256]
{
    __shared__ float sX[32][256];   // 32 KB
    const int tid  = threadIdx.x;
    const int row0 = blockIdx.x * 32;

    // stage X tile (32 rows x 256 = 8192 floats = 2048 float4), fully coalesced
    {
        const float4* xb4 = reinterpret_cast<const float4*>(X + (size_t)row0 * 256);
        float4* sx4 = reinterpret_cast<float4*>(&sX[0][0]);
        #pragma unroll
        for (int i = 0; i < 8; ++i) sx4[tid + i * 256] = xb4[tid + i * 256];
    }
    __syncthreads();

    const int c4 = (tid & 63) * 4;        // output col (4 consecutive)
    const int r0 = (tid >> 6) * 8;        // output row group (8 rows)

    float4 acc[8];
    #pragma unroll
    for (int i = 0; i < 8; ++i) acc[i] = make_float4(0.f, 0.f, 0.f, 0.f);

    #pragma unroll 4
    for (int d = 0; d < 256; ++d) {
        const float4 wv = *reinterpret_cast<const float4*>(&W1[d * 256 + c4]);
        #pragma unroll
        for (int i = 0; i < 8; ++i) {
            const float xv = sX[r0 + i][d];   // broadcast within wave
            acc[i].x = fmaf(xv, wv.x, acc[i].x);
            acc[i].y = fmaf(xv, wv.y, acc[i].y);
            acc[i].z = fmaf(xv, wv.z, acc[i].z);
            acc[i].w = fmaf(xv, wv.w, acc[i].w);
        }
    }

    const float4 bv = *reinterpret_cast<const float4*>(&b1[c4]);
    #pragma unroll
    for (int i = 0; i < 8; ++i) {
        float4 o = acc[i];
        o.x += bv.x; o.y += bv.y; o.z += bv.z; o.w += bv.w;
        *reinterpret_cast<float4*>(&A[(size_t)(row0 + r0 + i) * 256 + c4]) = o;
    }
}

// ---------------------------------------------------------------------------
// Kernel 2: fused  h1 = relu(me@W1b + A[gather])
//                  h2 = relu(h1@W2 + b2)
//                  out = h2@W3 + b3
// One block = 32 metric rows (all within one batch since 32 | 16384).
// 16384 blocks, 256 threads.
// ---------------------------------------------------------------------------
__global__ __launch_bounds__(256) void fused_mlp(
    const float* __restrict__ ME,   // [B*T, 64]
    const int*   __restrict__ SEG,  // [T]
    const float* __restrict__ A,    // [B*N, 256]
    const float* __restrict__ W1,   // [320, 256] (rows 256..319 = W1b)
    const float* __restrict__ W2,   // [256, 128]
    const float* __restrict__ b2,   // [128]
    const float* __restrict__ W3,   // [128]
    const float* __restrict__ b3,   // [1]
    float* __restrict__ OUT)        // [B*T]
{
    __shared__ float sME[32][64];    // 8 KB
    __shared__ float sH1[32][256];   // 32 KB
    const int tid   = threadIdx.x;
    const int grow0 = blockIdx.x * 32;          // global row = b*T + t

    // stage ME tile (32 x 64 = 2048 floats = 512 float4)
    {
        const float4* mb4 = reinterpret_cast<const float4*>(ME + (size_t)grow0 * MDIM);
        float4* sm4 = reinterpret_cast<float4*>(&sME[0][0]);
        #pragma unroll
        for (int i = 0; i < 2; ++i) sm4[tid + i * 256] = mb4[tid + i * 256];
    }
    __syncthreads();

    const float* __restrict__ W1b = W1 + 256 * 256;   // [64, 256]
    const int b = grow0 >> 14;                        // / 16384

    // -------- phase 1: h1 tile (32 rows x 256 cols) --------
    {
        const int c4 = (tid & 63) * 4;
        const int r0 = (tid >> 6) * 8;
        float4 acc[8];
        #pragma unroll
        for (int i = 0; i < 8; ++i) acc[i] = make_float4(0.f, 0.f, 0.f, 0.f);

        #pragma unroll 4
        for (int m = 0; m < MDIM; ++m) {
            const float4 wv = *reinterpret_cast<const float4*>(&W1b[m * 256 + c4]);
            #pragma unroll
            for (int i = 0; i < 8; ++i) {
                const float xv = sME[r0 + i][m];   // broadcast
                acc[i].x = fmaf(xv, wv.x, acc[i].x);
                acc[i].y = fmaf(xv, wv.y, acc[i].y);
                acc[i].z = fmaf(xv, wv.z, acc[i].z);
                acc[i].w = fmaf(xv, wv.w, acc[i].w);
            }
        }

        // epilogue: add gathered instance term, relu, store to LDS
        #pragma unroll
        for (int i = 0; i < 8; ++i) {
            const int r    = r0 + i;
            const int tloc = (grow0 & (TMET - 1)) + r;
            const int seg  = SEG[tloc];
            const float4 av = *reinterpret_cast<const float4*>(
                &A[(size_t)(b * NINST + seg) * 256 + c4]);
            float4 u = acc[i];
            u.x = fmaxf(u.x + av.x, 0.f);
            u.y = fmaxf(u.y + av.y, 0.f);
            u.z = fmaxf(u.z + av.z, 0.f);
            u.w = fmaxf(u.w + av.w, 0.f);
            *reinterpret_cast<float4*>(&sH1[r][c4]) = u;
        }
    }
    __syncthreads();

    // -------- phase 2+3: h2 (32 x 128) -> out (32) --------
    {
        const int c4 = (tid & 31) * 4;
        const int r0 = (tid >> 5) * 4;
        float4 acc2[4];
        #pragma unroll
        for (int i = 0; i < 4; ++i) acc2[i] = make_float4(0.f, 0.f, 0.f, 0.f);

        #pragma unroll 4
        for (int h = 0; h < HID; ++h) {
            const float4 wv = *reinterpret_cast<const float4*>(&W2[h * H2DIM + c4]);
            #pragma unroll
            for (int i = 0; i < 4; ++i) {
                const float xv = sH1[r0 + i][h];   // 2-way broadcast (free)
                acc2[i].x = fmaf(xv, wv.x, acc2[i].x);
                acc2[i].y = fmaf(xv, wv.y, acc2[i].y);
                acc2[i].z = fmaf(xv, wv.z, acc2[i].z);
                acc2[i].w = fmaf(xv, wv.w, acc2[i].w);
            }
        }

        const float4 b2v = *reinterpret_cast<const float4*>(&b2[c4]);
        const float4 w3v = *reinterpret_cast<const float4*>(&W3[c4]);
        const float  b3v = b3[0];

        #pragma unroll
        for (int i = 0; i < 4; ++i) {
            float4 u = acc2[i];
            u.x = fmaxf(u.x + b2v.x, 0.f);
            u.y = fmaxf(u.y + b2v.y, 0.f);
            u.z = fmaxf(u.z + b2v.z, 0.f);
            u.w = fmaxf(u.w + b2v.w, 0.f);
            float v = u.x * w3v.x + u.y * w3v.y + u.z * w3v.z + u.w * w3v.w;
            // reduce across the 32 lanes (tid&31) holding this row's 128 cols
            #pragma unroll
            for (int s = 16; s >= 1; s >>= 1) v += __shfl_xor(v, s);
            if ((tid & 31) == 0) OUT[(size_t)grow0 + r0 + i] = v + b3v;
        }
    }
}

// ---------------------------------------------------------------------------
extern "C" void kernel_launch(void* const* d_in, const int* in_sizes, int n_in,
                              void* d_out, int out_size, void* d_ws, size_t ws_size,
                              hipStream_t stream) {
    const float* h_inst = (const float*)d_in[0];   // [B, N, 256]
    const float* me     = (const float*)d_in[1];   // [B, T, 64]
    const int*   seg    = (const int*)d_in[2];     // [T]
    const float* W1     = (const float*)d_in[3];   // [320, 256]
    const float* b1     = (const float*)d_in[4];   // [256]
    const float* W2     = (const float*)d_in[5];   // [256, 128]
    const float* b2     = (const float*)d_in[6];   // [128]
    const float* W3     = (const float*)d_in[7];   // [128]
    const float* b3     = (const float*)d_in[8];   // [1]
    float* out = (float*)d_out;

    float* A = (float*)d_ws;   // [B*N, 256] = 16.8 MB scratch

    precomp_inst<<<(BATCH * NINST) / 32, 256, 0, stream>>>(h_inst, W1, b1, A);
    fused_mlp<<<(BATCH * TMET) / 32, 256, 0, stream>>>(me, seg, A, W1, W2, b2, W3, b3, out);
}

// Round 2
// 148.479 us; speedup vs baseline: 4.7724x; 4.7724x over previous
//
#include <hip/hip_runtime.h>

// B=32, N=512, D=256, M=64, HID=256, H2=128, T=16384, rows R=B*T=524288
typedef _Float16 f16;
typedef f16  f16x2 __attribute__((ext_vector_type(2)));
typedef f16  f16x8 __attribute__((ext_vector_type(8)));
typedef float f32x16 __attribute__((ext_vector_type(16)));
typedef int  i32x4 __attribute__((ext_vector_type(4)));
typedef unsigned int u32;

#define MFMA32 __builtin_amdgcn_mfma_f32_32x32x16_f16

static __device__ __forceinline__ f16x8 cvt8(float4 a, float4 b) {
    f16x8 v;
    v[0]=(f16)a.x; v[1]=(f16)a.y; v[2]=(f16)a.z; v[3]=(f16)a.w;
    v[4]=(f16)b.x; v[5]=(f16)b.y; v[6]=(f16)b.z; v[7]=(f16)b.w;
    return v;
}
static __device__ __forceinline__ u32 pack2(float a, float b) {
    f16x2 p; p[0]=(f16)a; p[1]=(f16)b;
    return __builtin_bit_cast(u32, p);
}
static __device__ __forceinline__ float2 unpack2(u32 w) {
    f16x2 h = __builtin_bit_cast(f16x2, w);
    return make_float2((float)h[0], (float)h[1]);
}

// ---------------------------------------------------------------------------
// Prepack: W1a (256x256), W1b (64x256), W2 (256x128) -> f16 MFMA A-operand
// fragment layout for 32x32x16: frag[mt][ks][lane][j] = W[k][col],
// k = 16*ks + 8*(lane>>5) + j, col = 32*mt + (lane&31).
// ---------------------------------------------------------------------------
__global__ __launch_bounds__(256) void prepack(
    const float* __restrict__ W1, const float* __restrict__ W2,
    f16* __restrict__ pa, f16* __restrict__ pb, f16* __restrict__ pc)
{
    const int idx = blockIdx.x * 256 + threadIdx.x;   // grid covers 114688
    int rel, fid, mt, ks;
    const int lane = (idx >> 3) & 63;
    const int j    = idx & 7;
    const int g8   = ((lane >> 5) << 3) + j;          // 8*(lane>>5)+j
    const int ln   = lane & 31;
    if (idx < 65536) {                 // W1a: [8 mt][16 ks]
        rel = idx; fid = rel >> 9; mt = fid >> 4; ks = fid & 15;
        int k = 16 * ks + g8, col = 32 * mt + ln;
        pa[rel] = (f16)W1[k * 256 + col];
    } else if (idx < 81920) {          // W1b: [8 mt][4 ks]
        rel = idx - 65536; fid = rel >> 9; mt = fid >> 2; ks = fid & 3;
        int k = 16 * ks + g8, col = 32 * mt + ln;
        pb[rel] = (f16)W1[(256 + k) * 256 + col];
    } else {                           // W2: [4 mt][16 ks]
        rel = idx - 81920; fid = rel >> 9; mt = fid >> 4; ks = fid & 15;
        int k = 16 * ks + g8, col = 32 * mt + ln;
        pc[rel] = (f16)W2[k * 128 + col];
    }
}

// ---------------------------------------------------------------------------
// Kernel 1: A[ir][c] = sum_k h[ir][k] * W1a[k][c] + b1[c], stored f16.
// Swapped MFMA: D[col][ir].  Block = 4 waves; each wave: 32 rows, 2 mt.
// ---------------------------------------------------------------------------
__global__ __launch_bounds__(256) void ainit(
    const float* __restrict__ H,       // [16384, 256]
    const f16x8* __restrict__ pW1a,    // [8][16][64] frags
    const float* __restrict__ B1,      // [256]
    f16* __restrict__ Af)              // [16384, 256]
{
    const int tid = threadIdx.x, wid = tid >> 6, lane = tid & 63;
    const int g = lane >> 5, ln = lane & 31;
    const long ir = (long)blockIdx.x * 32 + ln;

    // B-op fragments: h row, k = 16*ks + 8g + j
    const float4* h4 = (const float4*)(H + ir * 256);
    f16x8 hf[16];
    #pragma unroll
    for (int ks = 0; ks < 16; ++ks)
        hf[ks] = cvt8(h4[4 * ks + 2 * g], h4[4 * ks + 2 * g + 1]);

    const float4* b14 = (const float4*)B1;
    #pragma unroll
    for (int mi = 0; mi < 2; ++mi) {
        const int mt = wid * 2 + mi;
        f32x16 acc;
        #pragma unroll
        for (int q = 0; q < 4; ++q) {
            float4 bv = b14[8 * mt + 2 * q + g];
            acc[4*q+0] = bv.x; acc[4*q+1] = bv.y; acc[4*q+2] = bv.z; acc[4*q+3] = bv.w;
        }
        #pragma unroll
        for (int ks = 0; ks < 16; ++ks)
            acc = MFMA32(pW1a[(mt * 16 + ks) * 64 + lane], hf[ks], acc, 0, 0, 0);
        // store: cols (reg&3)+8*(reg>>2)+4g+32mt -> contiguous 4 per q
        #pragma unroll
        for (int q = 0; q < 4; ++q) {
            uint2 w;
            w.x = pack2(acc[4*q+0], acc[4*q+1]);
            w.y = pack2(acc[4*q+2], acc[4*q+3]);
            ((uint2*)Af)[ir * 64 + 8 * mt + 2 * q + g] = w;
        }
    }
}

// ---------------------------------------------------------------------------
// Fused: h1 = relu(me@W1b + A[seg]); h2 = relu(h1@W2 + b2); out = h2@W3 + b3
// Block = 8 waves (512 thr), 32 rows/wave = 256 rows/block, 2048 blocks.
// Swapped MFMA both layers; h1 transposed between layers via permlane32_swap.
// ---------------------------------------------------------------------------
__global__ __launch_bounds__(512, 2) void fused_mlp(
    const float* __restrict__ ME,      // [524288, 64]
    const int*   __restrict__ SEG,     // [16384]
    const f16*   __restrict__ Af,      // [16384, 256]
    const f16x8* __restrict__ pW1b,    // [8][4][64] frags
    const f16x8* __restrict__ pW2,     // [4][16][64] frags
    const float* __restrict__ B2,      // [128]
    const float* __restrict__ W3,      // [128]
    const float* __restrict__ B3,      // [1]
    float* __restrict__ OUT)           // [524288]
{
    __shared__ f16x8 sW2[4096];        // 64 KB, staged once
    const int tid = threadIdx.x, wid = tid >> 6, lane = tid & 63;
    const int g = lane >> 5, ln = lane & 31;

    #pragma unroll
    for (int i = 0; i < 8; ++i) sW2[i * 512 + tid] = pW2[i * 512 + tid];
    __syncthreads();

    const long grow = (long)blockIdx.x * 256 + wid * 32 + ln;  // metric row
    const int  tloc = (int)(grow & 16383);
    const int  b    = (int)(grow >> 14);
    const long arow = ((long)b << 9) + SEG[tloc];

    // ---- phase 1: h1[grow][0..255] (one row per lane, swapped MFMA) ----
    const float4* me4 = (const float4*)(ME + grow * 64);
    f16x8 mef[4];                       // B-op frags: k = 16s + 8g + j
    #pragma unroll
    for (int s = 0; s < 4; ++s)
        mef[s] = cvt8(me4[4 * s + 2 * g], me4[4 * s + 2 * g + 1]);

    u32 hp[8][8];                       // h1 packed f16 pairs, [mt][p]
    const uint2* A2 = (const uint2*)Af;
    #pragma unroll
    for (int mt = 0; mt < 8; ++mt) {
        f32x16 acc;
        #pragma unroll
        for (int q = 0; q < 4; ++q) {   // C-init = gathered A (has b1)
            uint2 av = A2[arow * 64 + 8 * mt + 2 * q + g];
            float2 lo = unpack2(av.x), hi = unpack2(av.y);
            acc[4*q+0] = lo.x; acc[4*q+1] = lo.y; acc[4*q+2] = hi.x; acc[4*q+3] = hi.y;
        }
        #pragma unroll
        for (int s = 0; s < 4; ++s)
            acc = MFMA32(pW1b[(mt * 4 + s) * 64 + lane], mef[s], acc, 0, 0, 0);
        // relu + pack: P[2q+t] = cols {8q+4g+2t, +1} (+32mt)
        #pragma unroll
        for (int q = 0; q < 4; ++q) {
            hp[mt][2*q+0] = pack2(fmaxf(acc[4*q+0], 0.f), fmaxf(acc[4*q+1], 0.f));
            hp[mt][2*q+1] = pack2(fmaxf(acc[4*q+2], 0.f), fmaxf(acc[4*q+3], 0.f));
        }
    }

    // ---- phase 2: h2 = h1 @ W2 (swapped), B-frags built via permlane ----
    f32x16 acc2[4];
    #pragma unroll
    for (int mt = 0; mt < 4; ++mt)
        #pragma unroll
        for (int i = 0; i < 16; ++i) acc2[mt][i] = 0.f;

    #pragma unroll
    for (int ks2 = 0; ks2 < 16; ++ks2) {
        const int mtp = ks2 >> 1, t = ks2 & 1;
        u32 w0 = hp[mtp][4*t+0], w1 = hp[mtp][4*t+1];
        u32 w2 = hp[mtp][4*t+2], w3 = hp[mtp][4*t+3];
        // exchange halves: lane<32 <-> lane>=32 (in-register transpose)
        asm("v_permlane32_swap_b32 %0, %1" : "+v"(w0), "+v"(w2));
        asm("v_permlane32_swap_b32 %0, %1" : "+v"(w1), "+v"(w3));
        i32x4 wv; wv[0] = (int)w0; wv[1] = (int)w1; wv[2] = (int)w2; wv[3] = (int)w3;
        const f16x8 bf = __builtin_bit_cast(f16x8, wv);
        #pragma unroll
        for (int mt = 0; mt < 4; ++mt)
            acc2[mt] = MFMA32(sW2[(mt * 16 + ks2) * 64 + lane], bf, acc2[mt], 0, 0, 0);
    }

    // ---- phase 3: out = relu(h2 + b2) . W3 + b3 ----
    const float4* b24 = (const float4*)B2;
    const float4* w34 = (const float4*)W3;
    float sum = 0.f;
    #pragma unroll
    for (int mt = 0; mt < 4; ++mt)
        #pragma unroll
        for (int q = 0; q < 4; ++q) {
            float4 bb = b24[8 * mt + 2 * q + g];
            float4 ww = w34[8 * mt + 2 * q + g];
            sum += fmaxf(acc2[mt][4*q+0] + bb.x, 0.f) * ww.x
                 + fmaxf(acc2[mt][4*q+1] + bb.y, 0.f) * ww.y
                 + fmaxf(acc2[mt][4*q+2] + bb.z, 0.f) * ww.z
                 + fmaxf(acc2[mt][4*q+3] + bb.w, 0.f) * ww.w;
        }
    sum += __shfl_xor(sum, 32, 64);     // combine col halves (g pairs)
    if (lane < 32) OUT[grow] = sum + B3[0];
}

// ---------------------------------------------------------------------------
extern "C" void kernel_launch(void* const* d_in, const int* in_sizes, int n_in,
                              void* d_out, int out_size, void* d_ws, size_t ws_size,
                              hipStream_t stream) {
    const float* h_inst = (const float*)d_in[0];
    const float* me     = (const float*)d_in[1];
    const int*   seg    = (const int*)d_in[2];
    const float* W1     = (const float*)d_in[3];
    const float* b1     = (const float*)d_in[4];
    const float* W2     = (const float*)d_in[5];
    const float* b2     = (const float*)d_in[6];
    const float* W3     = (const float*)d_in[7];
    const float* b3     = (const float*)d_in[8];
    float* out = (float*)d_out;

    char* ws = (char*)d_ws;
    f16* Af   = (f16*)ws;                                   // 8,388,608 B
    f16* pW1a = (f16*)(ws + 8388608);                       //   131,072 B
    f16* pW1b = (f16*)(ws + 8388608 + 131072);              //    32,768 B
    f16* pW2  = (f16*)(ws + 8388608 + 131072 + 32768);      //    65,536 B

    prepack<<<448, 256, 0, stream>>>(W1, W2, pW1a, pW1b, pW2);
    ainit<<<512, 256, 0, stream>>>(h_inst, (const f16x8*)pW1a, b1, Af);
    fused_mlp<<<2048, 512, 0, stream>>>(me, seg, Af, (const f16x8*)pW1b,
                                        (const f16x8*)pW2, b2, W3, b3, out);
}

// Round 3
// 128.146 us; speedup vs baseline: 5.5296x; 1.1587x over previous
//
#include <hip/hip_runtime.h>

// B=32, N=512, D=256, M=64, HID=256, H2=128, T=16384, rows R=B*T=524288
typedef _Float16 f16;
typedef f16  f16x2 __attribute__((ext_vector_type(2)));
typedef f16  f16x8 __attribute__((ext_vector_type(8)));
typedef float f32x16 __attribute__((ext_vector_type(16)));
typedef int  i32x4 __attribute__((ext_vector_type(4)));
typedef unsigned int u32;

#define MFMA32 __builtin_amdgcn_mfma_f32_32x32x16_f16
#define NT 4   // row-tiles (256 rows) per persistent block

static __device__ __forceinline__ f16x8 cvt8(float4 a, float4 b) {
    f16x8 v;
    v[0]=(f16)a.x; v[1]=(f16)a.y; v[2]=(f16)a.z; v[3]=(f16)a.w;
    v[4]=(f16)b.x; v[5]=(f16)b.y; v[6]=(f16)b.z; v[7]=(f16)b.w;
    return v;
}
static __device__ __forceinline__ u32 pack2(float a, float b) {
    f16x2 p; p[0]=(f16)a; p[1]=(f16)b;
    return __builtin_bit_cast(u32, p);
}
static __device__ __forceinline__ float2 unpack2(u32 w) {
    f16x2 h = __builtin_bit_cast(f16x2, w);
    return make_float2((float)h[0], (float)h[1]);
}

// ---------------------------------------------------------------------------
// Prepack: W1a (256x256), W1b (64x256), W2 (256x128) -> f16 MFMA A-operand
// fragment layout for 32x32x16: frag[mt][ks][lane][j] = W[k][col],
// k = 16*ks + 8*(lane>>5) + j, col = 32*mt + (lane&31).
// ---------------------------------------------------------------------------
__global__ __launch_bounds__(256) void prepack(
    const float* __restrict__ W1, const float* __restrict__ W2,
    f16* __restrict__ pa, f16* __restrict__ pb, f16* __restrict__ pc)
{
    const int idx = blockIdx.x * 256 + threadIdx.x;   // grid covers 114688
    int rel, fid, mt, ks;
    const int lane = (idx >> 3) & 63;
    const int j    = idx & 7;
    const int g8   = ((lane >> 5) << 3) + j;          // 8*(lane>>5)+j
    const int ln   = lane & 31;
    if (idx < 65536) {                 // W1a: [8 mt][16 ks]
        rel = idx; fid = rel >> 9; mt = fid >> 4; ks = fid & 15;
        int k = 16 * ks + g8, col = 32 * mt + ln;
        pa[rel] = (f16)W1[k * 256 + col];
    } else if (idx < 81920) {          // W1b: [8 mt][4 ks]
        rel = idx - 65536; fid = rel >> 9; mt = fid >> 2; ks = fid & 3;
        int k = 16 * ks + g8, col = 32 * mt + ln;
        pb[rel] = (f16)W1[(256 + k) * 256 + col];
    } else {                           // W2: [4 mt][16 ks]
        rel = idx - 81920; fid = rel >> 9; mt = fid >> 4; ks = fid & 15;
        int k = 16 * ks + g8, col = 32 * mt + ln;
        pc[rel] = (f16)W2[k * 128 + col];
    }
}

// ---------------------------------------------------------------------------
// Kernel 1: A[ir][c] = sum_k h[ir][k] * W1a[k][c] + b1[c], stored f16 in a
// gather-friendly permuted layout: uint2 index = ir*64 + g*32 + mt*4 + q
// (so one lane's 256B in fused_mlp is 16 contiguous dwordx4 loads).
// ---------------------------------------------------------------------------
__global__ __launch_bounds__(256) void ainit(
    const float* __restrict__ H,       // [16384, 256]
    const f16x8* __restrict__ pW1a,    // [8][16][64] frags
    const float* __restrict__ B1,      // [256]
    f16* __restrict__ Af)              // [16384, 256] permuted
{
    const int tid = threadIdx.x, wid = tid >> 6, lane = tid & 63;
    const int g = lane >> 5, ln = lane & 31;
    const long ir = (long)blockIdx.x * 32 + ln;

    // B-op fragments: h row, k = 16*ks + 8g + j
    const float4* h4 = (const float4*)(H + ir * 256);
    f16x8 hf[16];
    #pragma unroll
    for (int ks = 0; ks < 16; ++ks)
        hf[ks] = cvt8(h4[4 * ks + 2 * g], h4[4 * ks + 2 * g + 1]);

    const float4* b14 = (const float4*)B1;
    #pragma unroll
    for (int mi = 0; mi < 2; ++mi) {
        const int mt = wid * 2 + mi;
        f32x16 acc;
        #pragma unroll
        for (int q = 0; q < 4; ++q) {
            float4 bv = b14[8 * mt + 2 * q + g];
            acc[4*q+0] = bv.x; acc[4*q+1] = bv.y; acc[4*q+2] = bv.z; acc[4*q+3] = bv.w;
        }
        #pragma unroll
        for (int ks = 0; ks < 16; ++ks)
            acc = MFMA32(pW1a[(mt * 16 + ks) * 64 + lane], hf[ks], acc, 0, 0, 0);
        #pragma unroll
        for (int q = 0; q < 4; ++q) {
            uint2 w;
            w.x = pack2(acc[4*q+0], acc[4*q+1]);
            w.y = pack2(acc[4*q+2], acc[4*q+3]);
            ((uint2*)Af)[ir * 64 + g * 32 + mt * 4 + q] = w;
        }
    }
}

// ---------------------------------------------------------------------------
// Fused: h1 = relu(me@W1b + A[seg]); h2 = relu(h1@W2 + b2); out = h2@W3 + b3
// Persistent: 512 blocks x 8 waves; each wave does NT=4 tiles of 32 rows.
// Single-buffered software prefetch: next tile's A/ME loads are issued the
// moment the current copies are consumed. Layer1->layer2 interleaved per mt.
// ---------------------------------------------------------------------------
__global__ __launch_bounds__(512, 2) void fused_mlp(
    const float* __restrict__ ME,      // [524288, 64]
    const int*   __restrict__ SEG,     // [16384]
    const f16*   __restrict__ Af,      // [16384, 256] permuted
    const f16x8* __restrict__ pW1b,    // [8][4][64] frags (32KB, L1-resident)
    const f16x8* __restrict__ pW2,     // [4][16][64] frags
    const float* __restrict__ B2,      // [128]
    const float* __restrict__ W3,      // [128]
    const float* __restrict__ B3,      // [1]
    float* __restrict__ OUT)           // [524288]
{
    __shared__ f16x8 sW2[4096];        // 64 KB, staged once per block
    const int tid = threadIdx.x, wid = tid >> 6, lane = tid & 63;
    const int g = lane >> 5, ln = lane & 31;

    #pragma unroll
    for (int i = 0; i < 8; ++i) sW2[i * 512 + tid] = pW2[i * 512 + tid];
    __syncthreads();

    const long grow0 = (long)blockIdx.x * (NT * 256) + wid * 32 + ln;

    // prologue: segment gather rows for all NT tiles (one latency hop)
    int arow[NT];
    #pragma unroll
    for (int t = 0; t < NT; ++t) {
        const long gr = grow0 + t * 256;
        arow[t] = ((int)(gr >> 14) << 9) + SEG[(int)(gr & 16383)];
    }

    const uint4* AB = (const uint4*)Af;     // 16B units: row*32 + g*16 + mt*2 + u
    uint4  Av[16];                          // gathered A row (256B, f16-packed)
    float4 Mv[8];                           // ME row fragment halves (128B)

    #pragma unroll
    for (int mt = 0; mt < 8; ++mt) {
        Av[2*mt]   = AB[(long)arow[0] * 32 + g * 16 + mt * 2];
        Av[2*mt+1] = AB[(long)arow[0] * 32 + g * 16 + mt * 2 + 1];
    }
    {
        const float4* mb = (const float4*)(ME + grow0 * 64);
        #pragma unroll
        for (int s = 0; s < 4; ++s) {
            Mv[2*s]   = mb[4*s + 2*g];
            Mv[2*s+1] = mb[4*s + 2*g + 1];
        }
    }

    const float4* b24 = (const float4*)B2;
    const float4* w34 = (const float4*)W3;
    const float  b3v  = B3[0];

    #pragma unroll
    for (int t = 0; t < NT; ++t) {
        const long grow = grow0 + t * 256;

        // build ME fragments (consumes Mv), then immediately prefetch next ME
        f16x8 mef[4];
        #pragma unroll
        for (int s = 0; s < 4; ++s) mef[s] = cvt8(Mv[2*s], Mv[2*s+1]);
        if (t < NT - 1) {
            const float4* mb = (const float4*)(ME + (grow + 256) * 64);
            #pragma unroll
            for (int s = 0; s < 4; ++s) {
                Mv[2*s]   = mb[4*s + 2*g];
                Mv[2*s+1] = mb[4*s + 2*g + 1];
            }
        }

        f32x16 acc2[4];
        #pragma unroll
        for (int m2 = 0; m2 < 4; ++m2)
            #pragma unroll
            for (int i = 0; i < 16; ++i) acc2[m2][i] = 0.f;

        #pragma unroll
        for (int mt = 0; mt < 8; ++mt) {
            // C-init from gathered A (has b1 baked in)
            f32x16 acc;
            {
                const uint4 a0 = Av[2*mt], a1 = Av[2*mt+1];
                float2 f;
                f = unpack2(a0.x); acc[0]  = f.x; acc[1]  = f.y;
                f = unpack2(a0.y); acc[2]  = f.x; acc[3]  = f.y;
                f = unpack2(a0.z); acc[4]  = f.x; acc[5]  = f.y;
                f = unpack2(a0.w); acc[6]  = f.x; acc[7]  = f.y;
                f = unpack2(a1.x); acc[8]  = f.x; acc[9]  = f.y;
                f = unpack2(a1.y); acc[10] = f.x; acc[11] = f.y;
                f = unpack2(a1.z); acc[12] = f.x; acc[13] = f.y;
                f = unpack2(a1.w); acc[14] = f.x; acc[15] = f.y;
            }
            // regs just freed -> prefetch next tile's A chunk for this mt
            if (t < NT - 1) {
                Av[2*mt]   = AB[(long)arow[t+1] * 32 + g * 16 + mt * 2];
                Av[2*mt+1] = AB[(long)arow[t+1] * 32 + g * 16 + mt * 2 + 1];
            }
            #pragma unroll
            for (int s = 0; s < 4; ++s)
                acc = MFMA32(pW1b[(mt * 4 + s) * 64 + lane], mef[s], acc, 0, 0, 0);
            // relu + pack h1 (this mt's 32 cols) to f16 pairs
            u32 hpt[8];
            #pragma unroll
            for (int q = 0; q < 4; ++q) {
                hpt[2*q]   = pack2(fmaxf(acc[4*q+0], 0.f), fmaxf(acc[4*q+1], 0.f));
                hpt[2*q+1] = pack2(fmaxf(acc[4*q+2], 0.f), fmaxf(acc[4*q+3], 0.f));
            }
            // feed layer 2 immediately: ks2 = 2*mt + tt
            #pragma unroll
            for (int tt = 0; tt < 2; ++tt) {
                u32 w0 = hpt[4*tt+0], w1 = hpt[4*tt+1];
                u32 w2 = hpt[4*tt+2], w3 = hpt[4*tt+3];
                asm("v_permlane32_swap_b32 %0, %1" : "+v"(w0), "+v"(w2));
                asm("v_permlane32_swap_b32 %0, %1" : "+v"(w1), "+v"(w3));
                i32x4 wv; wv[0]=(int)w0; wv[1]=(int)w1; wv[2]=(int)w2; wv[3]=(int)w3;
                const f16x8 bf = __builtin_bit_cast(f16x8, wv);
                const int ks2 = 2*mt + tt;
                __builtin_amdgcn_s_setprio(1);
                #pragma unroll
                for (int m2 = 0; m2 < 4; ++m2)
                    acc2[m2] = MFMA32(sW2[(m2 * 16 + ks2) * 64 + lane], bf, acc2[m2], 0, 0, 0);
                __builtin_amdgcn_s_setprio(0);
            }
        }

        // phase 3: out = relu(h2 + b2) . W3 + b3
        float sum = 0.f;
        #pragma unroll
        for (int m2 = 0; m2 < 4; ++m2)
            #pragma unroll
            for (int q = 0; q < 4; ++q) {
                float4 bb = b24[8*m2 + 2*q + g];
                float4 ww = w34[8*m2 + 2*q + g];
                sum += fmaxf(acc2[m2][4*q+0] + bb.x, 0.f) * ww.x
                     + fmaxf(acc2[m2][4*q+1] + bb.y, 0.f) * ww.y
                     + fmaxf(acc2[m2][4*q+2] + bb.z, 0.f) * ww.z
                     + fmaxf(acc2[m2][4*q+3] + bb.w, 0.f) * ww.w;
            }
        sum += __shfl_xor(sum, 32, 64);     // combine col halves (g pair)
        if (lane < 32) OUT[grow] = sum + b3v;
    }
}

// ---------------------------------------------------------------------------
extern "C" void kernel_launch(void* const* d_in, const int* in_sizes, int n_in,
                              void* d_out, int out_size, void* d_ws, size_t ws_size,
                              hipStream_t stream) {
    const float* h_inst = (const float*)d_in[0];
    const float* me     = (const float*)d_in[1];
    const int*   seg    = (const int*)d_in[2];
    const float* W1     = (const float*)d_in[3];
    const float* b1     = (const float*)d_in[4];
    const float* W2     = (const float*)d_in[5];
    const float* b2     = (const float*)d_in[6];
    const float* W3     = (const float*)d_in[7];
    const float* b3     = (const float*)d_in[8];
    float* out = (float*)d_out;

    char* ws = (char*)d_ws;
    f16* Af   = (f16*)ws;                                   // 8,388,608 B
    f16* pW1a = (f16*)(ws + 8388608);                       //   131,072 B
    f16* pW1b = (f16*)(ws + 8388608 + 131072);              //    32,768 B
    f16* pW2  = (f16*)(ws + 8388608 + 131072 + 32768);      //    65,536 B

    prepack<<<448, 256, 0, stream>>>(W1, W2, pW1a, pW1b, pW2);
    ainit<<<512, 256, 0, stream>>>(h_inst, (const f16x8*)pW1a, b1, Af);
    fused_mlp<<<512, 512, 0, stream>>>(me, seg, Af, (const f16x8*)pW1b,
                                       (const f16x8*)pW2, b2, W3, b3, out);
}